// Round 7
// baseline (444.081 us; speedup 1.0000x reference)
//
#include <hip/hip_runtime.h>
#include <hip/hip_bf16.h>

// PSWarpHead round 7. fp32 I/O (proven r6). conv1 made branch-free:
//   xTp fully padded [b][y=-1..200][x=-1..176][c] bf16, halos zeroed
//   -> K-loop has NO conditionals: 8j x 9tap x (2 A-ld + 2 B-ld + 4 MFMA)
//   All 6 waves uniform (wave5 tile-1 computes garbage from in-buffer reads,
//   store-masked). feat1 fp32 [px][28]. ws 89.56 MB < 90.26 proven.

#define WDIM 176
#define HDIM 200
#define HWDIM 35200
#define CIN 256
#define PDIM 28
#define NBOX 2048
#define YP 202    // padded rows: y+1 in 0..201
#define XP 178    // padded cols: x+1 in 0..177

typedef __attribute__((ext_vector_type(8))) short bf16x8;
typedef __attribute__((ext_vector_type(4))) float floatx4;

__device__ __forceinline__ unsigned short f2bf(float f) {
    unsigned int u; __builtin_memcpy(&u, &f, 4);
    unsigned int r = u + 0x7FFFu + ((u >> 16) & 1u);   // RNE
    return (unsigned short)(r >> 16);
}

// ---------- zero halo rows/cols of xTp (ws re-poisoned every call) ----------
__global__ __launch_bounds__(256) void halo_zero_kernel(unsigned short* __restrict__ xTp) {
    int idx = blockIdx.x * 256 + threadIdx.x;   // 4 * 756 * 32 = 96768 exact
    int c8 = (idx & 31) * 8;
    int s = (idx >> 5) % 756;
    int b = (idx >> 5) / 756;
    int row, col;
    if (s < 356) { row = (s < 178) ? 0 : 201; col = (s < 178) ? s : s - 178; }
    else         { int t = s - 356; row = 1 + (t >> 1); col = (t & 1) ? 177 : 0; }
    unsigned short* p = xTp + ((long)(b * YP + row) * XP + col) * 256 + c8;
    ushort4 z = {0, 0, 0, 0};
    *(ushort4*)p = z;
    *(ushort4*)(p + 4) = z;
}

// ---------- transpose: fp32 x [b][c][y][x] -> bf16 xTp [b][y+1][x+1][c] ----------
// row-aligned 64-px tiles: x0 in {0,64,112} (tile 2 overlaps tile 1; identical writes)
__global__ __launch_bounds__(256) void transpose_kernel(const float* __restrict__ x,
                                                        unsigned short* __restrict__ xTp) {
    __shared__ unsigned short tile[32][80];
    int bx = blockIdx.x;                  // 600 = 200 y * 3 xt
    int y = bx / 3, xt = bx - y * 3;
    int x0 = (xt == 2) ? 112 : xt * 64;
    int c0 = blockIdx.y * 32, b = blockIdx.z;
    int t = threadIdx.x;
    int c_l = t >> 3, pxg = (t & 7) * 8;
    const float* sp = x + ((long)(b * CIN + c0 + c_l) * HDIM + y) * WDIM + x0 + pxg;
    float4 a = ((const float4*)sp)[0], bq = ((const float4*)sp)[1];
    tile[c_l][pxg + 0] = f2bf(a.x);  tile[c_l][pxg + 1] = f2bf(a.y);
    tile[c_l][pxg + 2] = f2bf(a.z);  tile[c_l][pxg + 3] = f2bf(a.w);
    tile[c_l][pxg + 4] = f2bf(bq.x); tile[c_l][pxg + 5] = f2bf(bq.y);
    tile[c_l][pxg + 6] = f2bf(bq.z); tile[c_l][pxg + 7] = f2bf(bq.w);
    __syncthreads();
    int px_l = t >> 2, cg = (t & 3) * 8;
    ushort4 o0, o1;
    o0.x = tile[cg + 0][px_l]; o0.y = tile[cg + 1][px_l];
    o0.z = tile[cg + 2][px_l]; o0.w = tile[cg + 3][px_l];
    o1.x = tile[cg + 4][px_l]; o1.y = tile[cg + 5][px_l];
    o1.z = tile[cg + 6][px_l]; o1.w = tile[cg + 7][px_l];
    unsigned short* dp = xTp + ((long)(b * YP + y + 1) * XP + x0 + px_l + 1) * 256 + c0 + cg;
    *(ushort4*)dp = o0;
    *(ushort4*)(dp + 4) = o1;
}

// ---------- prep: BwT[tap][n(32,pad0)][c] bf16; w2f fp32; BN fold ----------
__global__ void prep_kernel(const float* __restrict__ w1, const float* __restrict__ w2,
                            const float* __restrict__ g, const float* __restrict__ bt,
                            const float* __restrict__ mn, const float* __restrict__ vr,
                            unsigned short* __restrict__ BwT, float* __restrict__ w2f,
                            float* __restrict__ scale, float* __restrict__ shift) {
    int idx = blockIdx.x * 256 + threadIdx.x;
    if (idx < 9 * 32 * 256) {
        int tap = idx >> 13;
        int r = idx & 8191;
        int n = r >> 8, c = r & 255;
        BwT[idx] = (n < PDIM) ? f2bf(w1[n * 2304 + c * 9 + tap]) : (unsigned short)0;
    } else if (idx < 73728 + 784) {
        int i = idx - 73728;
        w2f[i] = w2[i];
    } else if (idx < 73728 + 784 + 32) {
        int p = idx - 73728 - 784;
        if (p < PDIM) {
            float inv = g[p] / sqrtf(vr[p] + 1e-3f);
            scale[p] = inv;
            shift[p] = bt[p] - mn[p] * inv;
        } else { scale[p] = 0.f; shift[p] = 0.f; }
    }
}

// ---------- conv1: branch-free MFMA K-loop ----------
// grid (200, 4), 384 thr = 6 waves. Wave w: px0 = w*32, 2 m-tiles x 2 n-tiles.
// Wave 5 m-tile 1 (px 176..191) reads stay in-buffer (garbage), store-masked.
__global__ __launch_bounds__(384) void conv1_kernel(const unsigned short* __restrict__ xTp,
                                                    const unsigned short* __restrict__ BwT,
                                                    const float* __restrict__ scale,
                                                    const float* __restrict__ shift,
                                                    float* __restrict__ feat1) {
    int y = blockIdx.x, b = blockIdx.y;
    int lane = threadIdx.x & 63, w = threadIdx.x >> 6;
    int lm = lane & 15, kg = lane >> 4;
    int px0 = w * 32;

    // stored row for dy in 0..2 is (y+1)+(dy-1) = y+dy; col for dx=0 is px+1
    const unsigned short* arow0 = xTp + ((long)(b * YP + y + 0) * XP) * 256;
    const unsigned short* arow1 = xTp + ((long)(b * YP + y + 1) * XP) * 256;
    const unsigned short* arow2 = xTp + ((long)(b * YP + y + 2) * XP) * 256;
    int colb = (px0 + lm + 1) * 256;   // element offset of lane's dx=0 column

    floatx4 acc[2][2] = {{{0.f,0.f,0.f,0.f},{0.f,0.f,0.f,0.f}},
                         {{0.f,0.f,0.f,0.f},{0.f,0.f,0.f,0.f}}};

    for (int j = 0; j < 8; j++) {
        int co = j * 32 + kg * 8;
#pragma unroll
        for (int tap = 0; tap < 9; tap++) {
            int dy = tap / 3, dx = tap % 3;
            const unsigned short* ar = (dy == 0) ? arow0 : (dy == 1) ? arow1 : arow2;
            const unsigned short* ap = ar + colb + (dx - 1) * 256 + co;
            bf16x8 a0 = *(const bf16x8*)ap;
            bf16x8 a1 = *(const bf16x8*)(ap + 16 * 256);
            const unsigned short* bp = BwT + ((tap * 32 + lm) << 8) + co;
            bf16x8 b0 = *(const bf16x8*)bp;
            bf16x8 b1 = *(const bf16x8*)(bp + 4096);
            acc[0][0] = __builtin_amdgcn_mfma_f32_16x16x32_bf16(a0, b0, acc[0][0], 0, 0, 0);
            acc[0][1] = __builtin_amdgcn_mfma_f32_16x16x32_bf16(a0, b1, acc[0][1], 0, 0, 0);
            acc[1][0] = __builtin_amdgcn_mfma_f32_16x16x32_bf16(a1, b0, acc[1][0], 0, 0, 0);
            acc[1][1] = __builtin_amdgcn_mfma_f32_16x16x32_bf16(a1, b1, acc[1][1], 0, 0, 0);
        }
    }

    // epilogue: C/D col = lane&15 (=n), row = (lane>>4)*4 + reg (=px offset)
    long pixbase = (long)b * HWDIM + (long)y * WDIM;
#pragma unroll
    for (int mt = 0; mt < 2; mt++) {
        if (px0 + mt * 16 < WDIM) {                 // masks wave-5 tile 1 only
#pragma unroll
            for (int nt = 0; nt < 2; nt++) {
                int n = nt * 16 + lm;
                if (n < PDIM) {
                    float sc = scale[n], sh = shift[n];
#pragma unroll
                    for (int r = 0; r < 4; r++) {
                        int px = px0 + mt * 16 + kg * 4 + r;
                        float v = fmaf(acc[mt][nt][r], sc, sh);
                        feat1[(pixbase + px) * PDIM + n] = v > 0.f ? v : 0.f;
                    }
                }
            }
        }
    }
}

// ---------- fused conv2(1x1) + rotated-grid PS bilinear sampler ----------
__device__ __forceinline__ float dot28(const float* __restrict__ row,
                                       const float* __restrict__ wv) {
    float s = 0.f;
#pragma unroll
    for (int i = 0; i < 7; i++) {
        float4 a = ((const float4*)row)[i];
        float4 b = ((const float4*)wv)[i];
        s = fmaf(a.x, b.x, s); s = fmaf(a.y, b.y, s);
        s = fmaf(a.z, b.z, s); s = fmaf(a.w, b.w, s);
    }
    return s;
}

__global__ __launch_bounds__(256) void sample_kernel(const float* __restrict__ boxes,
                                                     const float* __restrict__ feat1,
                                                     const float* __restrict__ w2f,
                                                     float* __restrict__ out) {
    int gid = blockIdx.x * 256 + threadIdx.x;
    int box = gid >> 5;              // 32 lanes per box
    int pl = gid & 31;
    int b = box >> 11;
    float val = 0.f;
    if (pl < PDIM) {
        long bb = (long)box * 7;
        float xg = boxes[bb + 0], yg = boxes[bb + 1];
        float wg = boxes[bb + 3], lg = boxes[bb + 4];
        float rg = boxes[bb + 6];
        float ct = cosf(rg), st = sinf(rg);
        const float lxv[4] = {-0.5f, -0.16666667f, 0.16666667f, 0.5f};
        const float lyv[7] = {-0.5f, -0.33333334f, -0.16666667f, 0.f,
                               0.16666667f, 0.33333334f, 0.5f};
        int h = pl / 7, ww = pl - (pl / 7) * 7;
        float xx = lxv[h] * wg;
        float yy = lyv[ww] * lg;
        float gx = (xx * ct + yy * st + xg) * 2.5f;           // GRID_OFF.x = 0
        float gy = (yy * ct - xx * st + yg + 40.f) * 2.5f;    // GRID_OFF.y = 40
        float x0 = floorf(gx), y0 = floorf(gy);
        float fx = gx - x0, fy = gy - y0;
        int xi = (int)x0, yi = (int)y0;
        const float* w2row = w2f + pl * PDIM;
        const float* base = feat1 + (long)b * HWDIM * PDIM;
        float Ia = 0.f, Ib = 0.f, Ic = 0.f, Id = 0.f;
        if (yi >= 0 && yi < HDIM) {
            if (xi >= 0 && xi < WDIM)         Ia = dot28(base + (long)(yi * WDIM + xi) * PDIM, w2row);
            if (xi + 1 >= 0 && xi + 1 < WDIM) Ic = dot28(base + (long)(yi * WDIM + xi + 1) * PDIM, w2row);
        }
        if (yi + 1 >= 0 && yi + 1 < HDIM) {
            if (xi >= 0 && xi < WDIM)         Ib = dot28(base + (long)((yi + 1) * WDIM + xi) * PDIM, w2row);
            if (xi + 1 >= 0 && xi + 1 < WDIM) Id = dot28(base + (long)((yi + 1) * WDIM + xi + 1) * PDIM, w2row);
        }
        val = (1.f - fx) * (1.f - fy) * Ia + (1.f - fx) * fy * Ib
            + fx * (1.f - fy) * Ic + fx * fy * Id;
    }
#pragma unroll
    for (int m = 16; m >= 1; m >>= 1) val += __shfl_xor(val, m, 64);
    if ((threadIdx.x & 31) == 0) {
        out[box] = val * (1.f / 28.f);
    }
}

// ---------- launch ----------
extern "C" void kernel_launch(void* const* d_in, const int* in_sizes, int n_in,
                              void* d_out, int out_size, void* d_ws, size_t ws_size,
                              hipStream_t stream) {
    const float* x     = (const float*)d_in[0];
    const float* boxes = (const float*)d_in[1];
    const float* w1    = (const float*)d_in[2];
    const float* g     = (const float*)d_in[3];
    const float* bt    = (const float*)d_in[4];
    const float* mn    = (const float*)d_in[5];
    const float* vr    = (const float*)d_in[6];
    const float* w2    = (const float*)d_in[7];
    float* out = (float*)d_out;

    char* ws = (char*)d_ws;
    unsigned short* xTp = (unsigned short*)ws;                 // 73,637,888 B
    float* feat1        = (float*)(ws + 73637888);             // 15,769,600 B
    unsigned short* BwT = (unsigned short*)(ws + 89407488);    //    147,456 B
    float* w2f          = (float*)(ws + 89554944);             //      3,136 B
    float* scale        = (float*)(ws + 89558080);             //        128 B
    float* shift        = (float*)(ws + 89558208);             //        128 B
    // total 89,558,336 B < 90,262,848 proven in round 2

    halo_zero_kernel<<<378, 256, 0, stream>>>(xTp);
    transpose_kernel<<<dim3(600, 8, 4), 256, 0, stream>>>(x, xTp);
    prep_kernel<<<292, 256, 0, stream>>>(w1, w2, g, bt, mn, vr, BwT, w2f, scale, shift);
    conv1_kernel<<<dim3(HDIM, 4), 384, 0, stream>>>(xTp, BwT, scale, shift, feat1);
    sample_kernel<<<1024, 256, 0, stream>>>(boxes, feat1, w2f, out);
}